// Round 1
// baseline (106.774 us; speedup 1.0000x reference)
//
#include <hip/hip_runtime.h>
#include <hip/hip_bf16.h>

#define NN 8192
#define DD 64

typedef __attribute__((ext_vector_type(8))) short short8;
typedef __attribute__((ext_vector_type(4))) float floatx4;

// ---------------- prep: per-row sum / sumsq in fp32, Z -> bf16 ----------------
__global__ __launch_bounds__(64) void prep_kernel(const float* __restrict__ Z,
                                                  unsigned short* __restrict__ Zb,
                                                  float* __restrict__ u,
                                                  float* __restrict__ v) {
    int row = blockIdx.x;
    int lane = threadIdx.x;
    float z = Z[(size_t)row * DD + lane];
    __hip_bfloat16 zb = __float2bfloat16(z);
    Zb[(size_t)row * DD + lane] = *(unsigned short*)&zb;
    float sq = z * z;
    float s = z;
    for (int off = 32; off; off >>= 1) {
        sq += __shfl_xor(sq, off);
        s  += __shfl_xor(s,  off);
    }
    if (lane == 0) {
        u[row] = sq + 2e-6f * s;   // sq_i + 2*eps*s_i
        v[row] = sq - 2e-6f * s;   // sq_j - 2*eps*s_j
    }
}

// ---------------- main: 128x128 tile per block, 4 waves of 64x64 ----------------
__global__ __launch_bounds__(256) void main_kernel(const unsigned short* __restrict__ Zb,
                                                   const float* __restrict__ u,
                                                   const float* __restrict__ v,
                                                   const float* __restrict__ alpha,
                                                   const int* __restrict__ A,
                                                   float* __restrict__ partials) {
    int bid = blockIdx.x;
    int bi = bid >> 6;        // N / 128 = 64 tiles per dim
    int bj = bid & 63;
    int tid = threadIdx.x;
    int wid = tid >> 6;
    int lane = tid & 63;
    int wr = wid >> 1, wc = wid & 1;
    int iBase = bi * 128 + wr * 64;
    int jBase = bj * 128 + wc * 64;
    int lhi = lane >> 4;      // 0..3
    int llo = lane & 15;      // 0..15
    int kb  = lhi * 8;        // k-offset within 32-wide k-step

    // Load MFMA fragments directly from global (Zb is ~1MB, L2-resident, reused 64x)
    short8 afrag[4][2], bfrag[4][2];
#pragma unroll
    for (int m = 0; m < 4; ++m) {
        const unsigned short* pa = &Zb[(size_t)(iBase + m * 16 + llo) * DD + kb];
        afrag[m][0] = *(const short8*)pa;
        afrag[m][1] = *(const short8*)(pa + 32);
        const unsigned short* pb = &Zb[(size_t)(jBase + m * 16 + llo) * DD + kb];
        bfrag[m][0] = *(const short8*)pb;
        bfrag[m][1] = *(const short8*)(pb + 32);
    }

    floatx4 acc[4][4];
#pragma unroll
    for (int m = 0; m < 4; ++m)
#pragma unroll
        for (int n = 0; n < 4; ++n)
            acc[m][n] = (floatx4){0.f, 0.f, 0.f, 0.f};

#pragma unroll
    for (int kk = 0; kk < 2; ++kk)
#pragma unroll
        for (int m = 0; m < 4; ++m)
#pragma unroll
            for (int n = 0; n < 4; ++n)
                acc[m][n] = __builtin_amdgcn_mfma_f32_16x16x32_bf16(
                    afrag[m][kk], bfrag[n][kk], acc[m][n], 0, 0, 0);

    // Hoist per-lane row/col stats. C/D layout: col = lane&15, row = (lane>>4)*4 + reg.
    float ui[16];
#pragma unroll
    for (int m = 0; m < 4; ++m)
#pragma unroll
        for (int r = 0; r < 4; ++r)
            ui[m * 4 + r] = u[iBase + m * 16 + lhi * 4 + r];
    float vj[4], aj[4];
#pragma unroll
    for (int n = 0; n < 4; ++n) {
        int j = jBase + n * 16 + llo;
        vj[n] = v[j];
        aj[n] = alpha[j];
    }

    const float deps2 = (float)DD * 1e-6f * 1e-6f;
    float ll = 0.f;
#pragma unroll
    for (int m = 0; m < 4; ++m) {
        int im = iBase + m * 16 + lhi * 4;
#pragma unroll
        for (int n = 0; n < 4; ++n) {
            int j = jBase + n * 16 + llo;
            const int* Ap = &A[(size_t)im * NN + j];
#pragma unroll
            for (int r = 0; r < 4; ++r) {
                float g = acc[m][n][r];
                float d2 = ui[m * 4 + r] + vj[n] - 2.f * g + deps2;
                float zd = sqrtf(fmaxf(d2, 0.f));
                float theta = aj[n] - zd;
                float af = (float)Ap[(size_t)r * NN];
                float sp = fmaxf(theta, 0.f) + __logf(1.f + __expf(-fabsf(theta)));
                int i = im + r;
                ll += theta * af - ((i == j) ? 0.f : sp);
            }
        }
    }

    // wave reduce then block reduce
    for (int off = 32; off; off >>= 1) ll += __shfl_xor(ll, off);
    __shared__ float red[4];
    if (lane == 0) red[wid] = ll;
    __syncthreads();
    if (tid == 0) partials[bid] = red[0] + red[1] + red[2] + red[3];
}

// ---------------- final deterministic reduction ----------------
__global__ __launch_bounds__(256) void final_kernel(const float* __restrict__ partials,
                                                    float* __restrict__ out) {
    int tid = threadIdx.x;
    float sum = 0.f;
    for (int idx = tid; idx < 4096; idx += 256) sum += partials[idx];
    for (int off = 32; off; off >>= 1) sum += __shfl_xor(sum, off);
    __shared__ float red[4];
    if ((tid & 63) == 0) red[tid >> 6] = sum;
    __syncthreads();
    if (tid == 0) out[0] = 0.5f * (red[0] + red[1] + red[2] + red[3]);
}

extern "C" void kernel_launch(void* const* d_in, const int* in_sizes, int n_in,
                              void* d_out, int out_size, void* d_ws, size_t ws_size,
                              hipStream_t stream) {
    const int*   A     = (const int*)d_in[0];
    const float* alpha = (const float*)d_in[1];
    const float* Z     = (const float*)d_in[2];
    float* out = (float*)d_out;

    char* ws = (char*)d_ws;
    unsigned short* Zb = (unsigned short*)ws;                    // N*D*2 = 1 MB
    float* u        = (float*)(ws + (size_t)NN * DD * 2);        // 32 KB
    float* v        = u + NN;                                    // 32 KB
    float* partials = v + NN;                                    // 4096 floats

    prep_kernel<<<NN, 64, 0, stream>>>(Z, Zb, u, v);
    main_kernel<<<4096, 256, 0, stream>>>(Zb, u, v, alpha, A, partials);
    final_kernel<<<1, 256, 0, stream>>>(partials, out);
}

// Round 2
// 88.905 us; speedup vs baseline: 1.2010x; 1.2010x over previous
//
#include <hip/hip_runtime.h>
#include <hip/hip_bf16.h>

#define NN 8192
#define DD 64

typedef __attribute__((ext_vector_type(8))) short short8;
typedef __attribute__((ext_vector_type(4))) float floatx4;

// ---------------- prep: per-row stats in fp32, Z -> bf16 ----------------
__global__ __launch_bounds__(64) void prep_kernel(const float* __restrict__ Z,
                                                  unsigned short* __restrict__ Zb,
                                                  float* __restrict__ u,
                                                  float* __restrict__ v) {
    int row = blockIdx.x;
    int lane = threadIdx.x;
    float z = Z[(size_t)row * DD + lane];
    __hip_bfloat16 zb = __float2bfloat16(z);
    Zb[(size_t)row * DD + lane] = *(unsigned short*)&zb;
    float sq = z * z;
    float s = z;
    for (int off = 32; off; off >>= 1) {
        sq += __shfl_xor(sq, off);
        s  += __shfl_xor(s,  off);
    }
    if (lane == 0) {
        const float deps2 = (float)DD * 1e-6f * 1e-6f;
        u[row] = sq + 2e-6f * s + deps2;  // sq_i + 2*eps*s_i + D*eps^2
        v[row] = sq - 2e-6f * s;          // sq_j - 2*eps*s_j
    }
}

// ---------------- main: 128x128 tile per block, 4 waves of 64x64 ----------------
// A-loads register-prefetched in 16-load batches, pipelined around the epilogue.
__global__ __launch_bounds__(256) void main_kernel(const unsigned short* __restrict__ Zb,
                                                   const float* __restrict__ u,
                                                   const float* __restrict__ v,
                                                   const float* __restrict__ alpha,
                                                   const int* __restrict__ A,
                                                   float* __restrict__ partials) {
    int bid = blockIdx.x;
    int bi = bid >> 6;        // N / 128 = 64 tiles per dim
    int bj = bid & 63;
    int tid = threadIdx.x;
    int wid = tid >> 6;
    int lane = tid & 63;
    int wr = wid >> 1, wc = wid & 1;
    int iBase = bi * 128 + wr * 64;
    int jBase = bj * 128 + wc * 64;
    int lhi = lane >> 4;      // 0..3
    int llo = lane & 15;      // 0..15
    int kb  = lhi * 8;        // k-offset within 32-wide k-step

    int Av[2][16];
#define LOADA(slot, mm)                                                              \
    {                                                                                \
        _Pragma("unroll") for (int n = 0; n < 4; ++n) {                              \
            const int* Ap = &A[(size_t)(iBase + (mm) * 16 + lhi * 4) * NN            \
                               + (jBase + n * 16 + llo)];                            \
            _Pragma("unroll") for (int r = 0; r < 4; ++r)                            \
                Av[slot][n * 4 + r] = Ap[(size_t)r * NN];                            \
        }                                                                            \
    }

    // batch 0 in flight during fragment loads + MFMA
    LOADA(0, 0);

    // MFMA fragments straight from global (Zb ~1MB, L2-resident, reused 64x)
    short8 afrag[4][2], bfrag[4][2];
#pragma unroll
    for (int m = 0; m < 4; ++m) {
        const unsigned short* pa = &Zb[(size_t)(iBase + m * 16 + llo) * DD + kb];
        afrag[m][0] = *(const short8*)pa;
        afrag[m][1] = *(const short8*)(pa + 32);
        const unsigned short* pb = &Zb[(size_t)(jBase + m * 16 + llo) * DD + kb];
        bfrag[m][0] = *(const short8*)pb;
        bfrag[m][1] = *(const short8*)(pb + 32);
    }

    // per-lane row/col stats (tiny, L2-hot). C/D layout: col = lane&15, row = (lane>>4)*4 + reg.
    float ui[16];
#pragma unroll
    for (int m = 0; m < 4; ++m)
#pragma unroll
        for (int r = 0; r < 4; ++r)
            ui[m * 4 + r] = u[iBase + m * 16 + lhi * 4 + r];
    float vj[4], aj[4];
#pragma unroll
    for (int n = 0; n < 4; ++n) {
        int j = jBase + n * 16 + llo;
        vj[n] = v[j];
        aj[n] = alpha[j];
    }

    floatx4 acc[4][4];
#pragma unroll
    for (int m = 0; m < 4; ++m)
#pragma unroll
        for (int n = 0; n < 4; ++n)
            acc[m][n] = (floatx4){0.f, 0.f, 0.f, 0.f};

#pragma unroll
    for (int kk = 0; kk < 2; ++kk)
#pragma unroll
        for (int m = 0; m < 4; ++m)
#pragma unroll
            for (int n = 0; n < 4; ++n)
                acc[m][n] = __builtin_amdgcn_mfma_f32_16x16x32_bf16(
                    afrag[m][kk], bfrag[n][kk], acc[m][n], 0, 0, 0);

    // batch 1 in flight while epilogue m=0 runs
    LOADA(1, 1);

    float ll = 0.f;
#pragma unroll
    for (int m = 0; m < 4; ++m) {
        const int slot = m & 1;
#pragma unroll
        for (int n = 0; n < 4; ++n) {
#pragma unroll
            for (int r = 0; r < 4; ++r) {
                float g = acc[m][n][r];
                float d2 = fmaf(-2.f, g, ui[m * 4 + r] + vj[n]);
                float zd = __builtin_amdgcn_sqrtf(fmaxf(d2, 0.f));
                float theta = aj[n] - zd;
                // branchless softplus: exact enough for theta in [-25, 4]
                float sp = __logf(1.f + __expf(theta));
                float af = (float)Av[slot][n * 4 + r];
                ll = fmaf(theta, af, ll) - sp;   // diagonal sp added back in final_kernel
            }
        }
        if (m == 0) LOADA(0, 2);
        if (m == 1) LOADA(1, 3);
    }

    // wave reduce then block reduce (fixed order -> deterministic)
    for (int off = 32; off; off >>= 1) ll += __shfl_xor(ll, off);
    __shared__ float red[4];
    if (lane == 0) red[wid] = ll;
    __syncthreads();
    if (tid == 0) partials[bid] = red[0] + red[1] + red[2] + red[3];
}

// ---------------- final deterministic reduction + diagonal softplus fixup ----------------
__global__ __launch_bounds__(256) void final_kernel(const float* __restrict__ partials,
                                                    const float* __restrict__ alpha,
                                                    float* __restrict__ out) {
    int tid = threadIdx.x;
    float sum = 0.f;
    for (int idx = tid; idx < 4096; idx += 256) sum += partials[idx];
    // + trace(softplus(theta)): theta_ii = alpha_i - sqrt(D*eps^2) = alpha_i - 8e-6
    float diag = 0.f;
    for (int i = tid; i < NN; i += 256) {
        float th = alpha[i] - 8e-6f;
        diag += __logf(1.f + __expf(th));
    }
    float tot = sum + diag;
    for (int off = 32; off; off >>= 1) tot += __shfl_xor(tot, off);
    __shared__ float red[4];
    if ((tid & 63) == 0) red[tid >> 6] = tot;
    __syncthreads();
    if (tid == 0) out[0] = 0.5f * (red[0] + red[1] + red[2] + red[3]);
}

extern "C" void kernel_launch(void* const* d_in, const int* in_sizes, int n_in,
                              void* d_out, int out_size, void* d_ws, size_t ws_size,
                              hipStream_t stream) {
    const int*   A     = (const int*)d_in[0];
    const float* alpha = (const float*)d_in[1];
    const float* Z     = (const float*)d_in[2];
    float* out = (float*)d_out;

    char* ws = (char*)d_ws;
    unsigned short* Zb = (unsigned short*)ws;                    // N*D*2 = 1 MB
    float* u        = (float*)(ws + (size_t)NN * DD * 2);        // 32 KB
    float* v        = u + NN;                                    // 32 KB
    float* partials = v + NN;                                    // 4096 floats

    prep_kernel<<<NN, 64, 0, stream>>>(Z, Zb, u, v);
    main_kernel<<<4096, 256, 0, stream>>>(Zb, u, v, alpha, A, partials);
    final_kernel<<<1, 256, 0, stream>>>(partials, alpha, out);
}